// Round 3
// baseline (656.891 us; speedup 1.0000x reference)
//
#include <hip/hip_runtime.h>
#include <math.h>

#define BATCH 64
#define ADIM  1152
#define BDIM  32
#define SLICE 512                 // BDIM*POSE floats per (bt, a) row
#define CHUNKS 8
#define ROWS  144                 // rows per block = ADIM/CHUNKS
#define RPW   36                  // rows per wave (4 waves/block)
#define EPSQ  1e-6f
#define SPART_ITER ((size_t)BATCH * CHUNKS * SLICE)   // floats per iter region

typedef float v4f __attribute__((ext_vector_type(4)));

// ---------------------------------------------------------------------------
// Fragment layout: v4f slot s of a 512-float capsule vector holds b = s>>2,
// poses 4*(s&3)+k. Wave lane l owns slots l (b=l>>2) and 64+l (b=16+(l>>2)).
// ---------------------------------------------------------------------------

__device__ __forceinline__ void squash_from(const float* sp, int lane,
                                            v4f& sA, v4f& sB, v4f& fac) {
    const v4f* spv = (const v4f*)sp;
    sA = (v4f){0.f, 0.f, 0.f, 0.f};
    sB = (v4f){0.f, 0.f, 0.f, 0.f};
#pragma unroll
    for (int c = 0; c < CHUNKS; ++c) {
        sA += spv[c * 128 + lane];
        sB += spv[c * 128 + 64 + lane];
    }
    v4f nq = sA * sA + sB * sB;
#pragma unroll
    for (int off = 4; off <= 32; off <<= 1) {
        nq.x += __shfl_xor(nq.x, off, 64);
        nq.y += __shfl_xor(nq.y, off, 64);
        nq.z += __shfl_xor(nq.z, off, 64);
        nq.w += __shfl_xor(nq.w, off, 64);
    }
    fac.x = sqrtf(nq.x + EPSQ) / (1.f + nq.x);
    fac.y = sqrtf(nq.y + EPSQ) / (1.f + nq.y);
    fac.z = sqrtf(nq.z + EPSQ) / (1.f + nq.z);
    fac.w = sqrtf(nq.w + EPSQ) / (1.f + nq.w);
}

__device__ __forceinline__ void reduce_write(v4f* red, int lane, int wv,
                                             v4f ra, v4f rb, float* dst) {
    __syncthreads();
    if (wv == 3) { red[lane] = ra; red[64 + lane] = rb; }
    __syncthreads();
    if (wv == 2) { red[lane] += ra; red[64 + lane] += rb; }
    __syncthreads();
    if (wv == 1) { red[lane] += ra; red[64 + lane] += rb; }
    __syncthreads();
    if (wv == 0) {
        v4f* sp = (v4f*)dst;
        sp[lane]      = red[lane] + ra;
        sp[64 + lane] = red[64 + lane] + rb;
    }
}

// canonical threadFenceReduction-style publish / observe (device scope,
// safe across XCDs per Guideline 16)
__device__ __forceinline__ void bar_release(unsigned* c) {
    __threadfence();              // every thread orders its prior stores
    __syncthreads();              // all fences done before the signal
    if (threadIdx.x == 0)
        __hip_atomic_fetch_add(c, 1u, __ATOMIC_RELEASE,
                               __HIP_MEMORY_SCOPE_AGENT);
}

__device__ __forceinline__ void bar_wait(unsigned* c, unsigned target) {
    if (threadIdx.x == 0) {
        while (__hip_atomic_load(c, __ATOMIC_RELAXED,
                                 __HIP_MEMORY_SCOPE_AGENT) < target)
            __builtin_amdgcn_s_sleep(2);
        (void)__hip_atomic_load(c, __ATOMIC_ACQUIRE,
                                __HIP_MEMORY_SCOPE_AGENT);
    }
    __syncthreads();
    __threadfence();              // acquire-side cache discipline for all lanes
}

// one routing sweep over this wave's 36 rows: c = softmax_b(logits + psum.v),
// acc += c*v. 3-row groups, ping-pong prefetch (6 v4f in flight).
__device__ __forceinline__ void iter_sweep(const v4f* vw, const float* lg,
                                           int lane, int bq, int r0,
                                           v4f pA, v4f pB,
                                           v4f& acc0, v4f& acc1) {
    acc0 = (v4f){0.f, 0.f, 0.f, 0.f};
    acc1 = (v4f){0.f, 0.f, 0.f, 0.f};
    v4f fA[6], fB[6];
#pragma unroll
    for (int u = 0; u < 6; ++u) fA[u] = vw[lane + 64 * u];
#pragma unroll 2
    for (int g = 0; g < 12; ++g) {
        v4f* cur = (g & 1) ? fB : fA;
        v4f* nxt = (g & 1) ? fA : fB;
        if (g + 1 < 12) {
#pragma unroll
            for (int u = 0; u < 6; ++u)
                nxt[u] = vw[lane + 64 * ((g + 1) * 6 + u)];
        }
#pragma unroll
        for (int i = 0; i < 3; ++i) {
            const int rw = r0 + 3 * g + i;
            v4f va = cur[2 * i], vb = cur[2 * i + 1];
            float b0 = lg[rw * BDIM + bq];
            float b1 = lg[rw * BDIM + 16 + bq];
            float d0 = pA.x * va.x + pA.y * va.y + pA.z * va.z + pA.w * va.w;
            float d1 = pB.x * vb.x + pB.y * vb.y + pB.z * vb.z + pB.w * vb.w;
            d0 += __shfl_xor(d0, 1, 64); d0 += __shfl_xor(d0, 2, 64);
            d1 += __shfl_xor(d1, 1, 64); d1 += __shfl_xor(d1, 2, 64);
            float e0 = __expf(b0 + d0);
            float e1 = __expf(b1 + d1);
            float uu = e0 + e1;
#pragma unroll
            for (int off = 4; off <= 32; off <<= 1)
                uu += __shfl_xor(uu, off, 64);
            float rdc = __builtin_amdgcn_rcpf(uu);
            acc0 += (e0 * rdc) * va;
            acc1 += (e1 * rdc) * vb;
        }
    }
}

__global__ void zero_cnt(unsigned* cnt) {
    if (threadIdx.x < BATCH) cnt[threadIdx.x] = 0u;
}

// ---------------------------------------------------------------------------
// One fused kernel: 512 blocks = 64 bt x 8 chunks, 256 threads.
// __launch_bounds__(256,4): VGPR<=128, LDS 38KB -> hard cap 4 blocks/CU ->
// 1024 resident slots for 512 blocks (2x slack) => per-bt spin barriers are
// deadlock-free. Phases per block: iter0 sweep (v from HBM, populates L3),
// barrier(8), squash; iter1 sweep (v from L3), barrier(16), squash; iter2
// sweep, barrier(24), chunk-0 block emits outputs. Different bts overlap
// freely -- no global drains, 2 launches total.
// ---------------------------------------------------------------------------
__global__ __launch_bounds__(256, 4) void route_all(
    const float* __restrict__ v,       // [BATCH][ADIM][BDIM][POSE]
    const float* __restrict__ logits,  // [ADIM][BDIM]
    float* s_part,                     // [3][BATCH][CHUNKS][SLICE]
    unsigned* cnt,                     // [BATCH]
    float* __restrict__ out)           // a_out (8192) ++ p (32768)
{
    const int bt    = blockIdx.x >> 3;
    const int chunk = blockIdx.x & 7;
    const int t     = threadIdx.x;
    const int lane  = t & 63;
    const int wv    = t >> 6;
    const int bq    = lane >> 2;
    const int a0    = chunk * ROWS;
    const int r0    = wv * RPW;

    __shared__ float lg_sh[ROWS * BDIM];  // raw logits       18 KB
    __shared__ float w_sh[ROWS * BDIM];   // softmax(logits)  18 KB
    __shared__ v4f   red[128];            //                   2 KB

    if (t < ROWS) {
        const float* lr = logits + (size_t)(a0 + t) * BDIM;
        float e[BDIM];
        float s = 0.f;
#pragma unroll
        for (int b = 0; b < BDIM; ++b) {
            float x = lr[b];
            lg_sh[t * BDIM + b] = x;
            e[b] = __expf(x);
            s += e[b];
        }
        float rd = 1.f / s;
#pragma unroll
        for (int b = 0; b < BDIM; ++b) w_sh[t * BDIM + b] = e[b] * rd;
    }
    __syncthreads();

    const v4f* vw = (const v4f*)(v + ((size_t)bt * ADIM + a0 + r0) * SLICE);
    unsigned* cb = cnt + bt;

    // ---- iter 0: stream v (cached -> allocates L3), weights from w_sh ----
    v4f acc0 = (v4f){0.f, 0.f, 0.f, 0.f};
    v4f acc1 = (v4f){0.f, 0.f, 0.f, 0.f};
    {
        v4f fA[6], fB[6];
#pragma unroll
        for (int u = 0; u < 6; ++u) fA[u] = vw[lane + 64 * u];
#pragma unroll 2
        for (int kk = 0; kk < 12; ++kk) {
            v4f* cur = (kk & 1) ? fB : fA;
            v4f* nxt = (kk & 1) ? fA : fB;
            if (kk + 1 < 12) {
#pragma unroll
                for (int u = 0; u < 6; ++u)
                    nxt[u] = vw[lane + 64 * ((kk + 1) * 6 + u)];
            }
#pragma unroll
            for (int u = 0; u < 6; ++u) {
                const int j  = kk * 6 + u;
                const int rw = r0 + (j >> 1);
                if ((j & 1) == 0) acc0 += w_sh[rw * BDIM + bq] * cur[u];
                else              acc1 += w_sh[rw * BDIM + 16 + bq] * cur[u];
            }
        }
    }
    reduce_write(red, lane, wv, acc0, acc1,
                 s_part + ((size_t)bt * CHUNKS + chunk) * SLICE);
    bar_release(cb);
    bar_wait(cb, 8);

    v4f sA, sB, fac;
    squash_from(s_part + (size_t)bt * CHUNKS * SLICE, lane, sA, sB, fac);
    v4f pA = fac * sA;
    v4f pB = fac * sB;

    // ---- iter 1 (v from L3) ----
    iter_sweep(vw, lg_sh, lane, bq, r0, pA, pB, acc0, acc1);
    reduce_write(red, lane, wv, acc0, acc1,
                 s_part + SPART_ITER + ((size_t)bt * CHUNKS + chunk) * SLICE);
    bar_release(cb);
    bar_wait(cb, 16);

    squash_from(s_part + SPART_ITER + (size_t)bt * CHUNKS * SLICE,
                lane, sA, sB, fac);
    pA += fac * sA;
    pB += fac * sB;

    // ---- iter 2 ----
    iter_sweep(vw, lg_sh, lane, bq, r0, pA, pB, acc0, acc1);
    reduce_write(red, lane, wv, acc0, acc1,
                 s_part + 2 * SPART_ITER + ((size_t)bt * CHUNKS + chunk) * SLICE);
    bar_release(cb);

    if (chunk != 0) return;
    bar_wait(cb, 24);
    if (wv != 0) return;

    // ---- final outputs (wave 0 of chunk-0 block per bt) ----
    squash_from(s_part + 2 * SPART_ITER + (size_t)bt * CHUNKS * SLICE,
                lane, sA, sB, fac);
    v4f p2A = fac * sA;
    v4f p2B = fac * sB;
    v4f* pg = (v4f*)(out + 8192 + (size_t)bt * SLICE);
    pg[lane]      = p2A;      // b = bq,     poses 4q+k
    pg[64 + lane] = p2B;      // b = 16+bq
    // a_out[bt][b][p2] = sqrt(sum_p1 p[b][4*p1+p2]^2): reduce over q via xor-1,2
    v4f qa = p2A * p2A;
    v4f qb = p2B * p2B;
#pragma unroll
    for (int off = 1; off <= 2; off <<= 1) {
        qa.x += __shfl_xor(qa.x, off, 64); qa.y += __shfl_xor(qa.y, off, 64);
        qa.z += __shfl_xor(qa.z, off, 64); qa.w += __shfl_xor(qa.w, off, 64);
        qb.x += __shfl_xor(qb.x, off, 64); qb.y += __shfl_xor(qb.y, off, 64);
        qb.z += __shfl_xor(qb.z, off, 64); qb.w += __shfl_xor(qb.w, off, 64);
    }
    if ((lane & 3) == 0) {
        v4f ra, rb;
        ra.x = sqrtf(qa.x); ra.y = sqrtf(qa.y);
        ra.z = sqrtf(qa.z); ra.w = sqrtf(qa.w);
        rb.x = sqrtf(qb.x); rb.y = sqrtf(qb.y);
        rb.z = sqrtf(qb.z); rb.w = sqrtf(qb.w);
        v4f* ag = (v4f*)(out + (size_t)bt * 128);
        ag[bq]      = ra;
        ag[16 + bq] = rb;
    }
}

extern "C" void kernel_launch(void* const* d_in, const int* in_sizes, int n_in,
                              void* d_out, int out_size, void* d_ws, size_t ws_size,
                              hipStream_t stream) {
    const float* v      = (const float*)d_in[1];   // (64,1152,32,4,4,1)
    const float* logits = (const float*)d_in[2];   // (1,1152,32,1,1,1)
    float* out    = (float*)d_out;
    float* s_part = (float*)d_ws;                  // 3 MiB, written before read
    unsigned* cnt = (unsigned*)((char*)d_ws + 3 * SPART_ITER * sizeof(float));

    zero_cnt<<<dim3(1), dim3(64), 0, stream>>>(cnt);
    route_all<<<dim3(BATCH * CHUNKS), dim3(256), 0, stream>>>(
        v, logits, s_part, cnt, out);
}

// Round 4
// 253.862 us; speedup vs baseline: 2.5876x; 2.5876x over previous
//
#include <hip/hip_runtime.h>
#include <math.h>

#define BATCH 64
#define ADIM  1152
#define BDIM  32
#define POSE  16
#define SLICE 512                 // BDIM*POSE floats per (bt, a) row
#define CHUNKS 16
#define ROWS  72                  // rows per block = ADIM/CHUNKS
#define RPW   18                  // rows per wave (4 waves/block)
#define WAVES 4
#define EPSQ  1e-6f
#define SPART_ITER ((size_t)BATCH * CHUNKS * SLICE)

typedef float v4f __attribute__((ext_vector_type(4)));

// pack two floats -> bf16x2 (round-to-nearest-even)
__device__ __forceinline__ unsigned pack_bf16x2(float a, float b) {
    unsigned ua = __float_as_uint(a), ub = __float_as_uint(b);
    ua = (ua + 0x7fffu + ((ua >> 16) & 1u)) >> 16;
    ub = (ub + 0x7fffu + ((ub >> 16) & 1u));
    return (ua & 0xffffu) | (ub & 0xffff0000u);
}

__device__ __forceinline__ v4f unpack_bf16x4(uint2 w) {
    v4f r;
    r.x = __uint_as_float(w.x << 16);
    r.y = __uint_as_float(w.x & 0xffff0000u);
    r.z = __uint_as_float(w.y << 16);
    r.w = __uint_as_float(w.y & 0xffff0000u);
    return r;
}

// ---------------------------------------------------------------------------
// s_part layout: [iter][bt][chunk][SLICE]; v4f slot s of a 512-float capsule
// vector holds b = s>>2, poses 4*(s&3)+k. Wave lane l owns slots l (b=l>>2)
// and 64+l (b=16+(l>>2)).
// ---------------------------------------------------------------------------

// Reduce 16 chunk partials of one batch, then squash. n[pose] = sum_b s^2
// reduced over the 16 lanes sharing l&3 via xor-4..32 shuffles.
__device__ __forceinline__ void squash_from(const float* sp, int lane,
                                            v4f& sA, v4f& sB, v4f& fac) {
    const v4f* spv = (const v4f*)sp;
    sA = (v4f){0.f, 0.f, 0.f, 0.f};
    sB = (v4f){0.f, 0.f, 0.f, 0.f};
#pragma unroll
    for (int c = 0; c < CHUNKS; ++c) {
        sA += spv[c * 128 + lane];
        sB += spv[c * 128 + 64 + lane];
    }
    v4f nq = sA * sA + sB * sB;
#pragma unroll
    for (int off = 4; off <= 32; off <<= 1) {
        nq.x += __shfl_xor(nq.x, off, 64);
        nq.y += __shfl_xor(nq.y, off, 64);
        nq.z += __shfl_xor(nq.z, off, 64);
        nq.w += __shfl_xor(nq.w, off, 64);
    }
    fac.x = sqrtf(nq.x + EPSQ) / (1.f + nq.x);
    fac.y = sqrtf(nq.y + EPSQ) / (1.f + nq.y);
    fac.z = sqrtf(nq.z + EPSQ) / (1.f + nq.z);
    fac.w = sqrtf(nq.w + EPSQ) / (1.f + nq.w);
}

// cross-wave reduce of per-wave partials; wv0 writes slots lane / 64+lane
__device__ __forceinline__ void reduce_write(v4f* red, int lane, int wv,
                                             v4f ra, v4f rb, float* dst) {
    __syncthreads();
    if (wv == 3) { red[lane] = ra; red[64 + lane] = rb; }
    __syncthreads();
    if (wv == 2) { red[lane] += ra; red[64 + lane] += rb; }
    __syncthreads();
    if (wv == 1) { red[lane] += ra; red[64 + lane] += rb; }
    __syncthreads();
    if (wv == 0) {
        v4f* sp = (v4f*)dst;
        sp[lane]      = red[lane] + ra;
        sp[64 + lane] = red[64 + lane] + rb;
    }
}

// ---------------------------------------------------------------------------
// Pass 0 (proven in baseline): stream fp32 v once (coalesced, nontemporal),
// write bf16 tile (cached -> L3-resident for iters), accumulate
// s0 = sum_a softmax(logits)*v from full-precision data in the same loop.
// ---------------------------------------------------------------------------
__global__ __launch_bounds__(256) void route0_compress(
    const float* __restrict__ v,       // [BATCH][ADIM][BDIM][POSE]
    const float* __restrict__ logits,  // [ADIM][BDIM]
    uint2* __restrict__ tile,          // bf16 copy of v, same layout
    float* __restrict__ s_part)        // [BATCH][CHUNKS][SLICE]
{
    const int bt    = blockIdx.x >> 4;
    const int chunk = blockIdx.x & 15;
    const int t     = threadIdx.x;
    const int bc0   = (t >> 2) & 31;   // fixed b of this thread's stream slots
    const int hi    = t >> 7;          // row = 2k + hi for f4-index i = t + 256k
    const int a0    = chunk * ROWS;

    __shared__ float w_sh[ROWS * BDIM];   // 9 KB: softmax(logits) weights
    __shared__ v4f   red[128];            // 2 KB

    if (t < ROWS) {
        const float* lr = logits + (size_t)(a0 + t) * BDIM;
        float s = 0.f;
        float e[BDIM];
#pragma unroll
        for (int b = 0; b < BDIM; ++b) { e[b] = __expf(lr[b]); s += e[b]; }
        float rd = 1.f / s;
#pragma unroll
        for (int b = 0; b < BDIM; ++b) w_sh[t * BDIM + b] = e[b] * rd;
    }
    __syncthreads();

    const v4f* vg = (const v4f*)(v + ((size_t)bt * ADIM + a0) * SLICE);
    uint2*     tg = tile + ((size_t)bt * ADIM + a0) * 128;

    v4f acc = (v4f){0.f, 0.f, 0.f, 0.f};
    v4f fA[6], fB[6];
#pragma unroll
    for (int u = 0; u < 6; ++u)
        fA[u] = __builtin_nontemporal_load(&vg[t + 256 * u]);

#pragma unroll
    for (int kk = 0; kk < 6; ++kk) {
        v4f* cur = (kk & 1) ? fB : fA;
        v4f* nxt = (kk & 1) ? fA : fB;
        if (kk + 1 < 6) {
#pragma unroll
            for (int u = 0; u < 6; ++u)
                nxt[u] = __builtin_nontemporal_load(&vg[t + 256 * ((kk + 1) * 6 + u)]);
        }
#pragma unroll
        for (int u = 0; u < 6; ++u) {
            const int k   = kk * 6 + u;
            const int i   = t + 256 * k;
            const int row = 2 * k + hi;
            tg[i] = make_uint2(pack_bf16x2(cur[u].x, cur[u].y),
                               pack_bf16x2(cur[u].z, cur[u].w));
            float c0 = w_sh[row * BDIM + bc0];
            acc += c0 * cur[u];
        }
    }

    // pair-reduce (t, t+128): thread t<128 owns f4 slot t of the s vector
    __syncthreads();
    if (t >= 128) red[t - 128] = acc;
    __syncthreads();
    if (t < 128) {
        acc += red[t];
        ((v4f*)(s_part + ((size_t)bt * CHUNKS + chunk) * SLICE))[t] = acc;
    }
}

// ---------------------------------------------------------------------------
// Iteration pass (iters 1 and 2) from the bf16 tile. psum = sum_{j<nprev}
// squash(s_j), recomputed redundantly per block from L2-resident s_part
// (identical arithmetic -> bitwise-identical psum everywhere). 3-row
// ping-pong prefetch (6 uint2 = 48 B/lane in flight) over the L3-resident
// tile. No max-subtract: |b| bounded (~20) in fp32.
// ---------------------------------------------------------------------------
__global__ __launch_bounds__(256) void iter_tile(
    const uint2* __restrict__ tile,
    const float* __restrict__ logits,
    const float* __restrict__ s_part,  // [3][BATCH][CHUNKS][SLICE], regions 0..nprev-1
    float* __restrict__ s_next,        // [BATCH][CHUNKS][SLICE]
    int nprev)
{
    const int bt    = blockIdx.x >> 4;
    const int chunk = blockIdx.x & 15;
    const int t     = threadIdx.x;
    const int lane  = t & 63;
    const int wv    = t >> 6;
    const int bq    = lane >> 2;
    const int a0    = chunk * ROWS;
    const int r0    = wv * RPW;

    __shared__ v4f red[128];           // 2 KB

    v4f pA = (v4f){0.f, 0.f, 0.f, 0.f};
    v4f pB = (v4f){0.f, 0.f, 0.f, 0.f};
    for (int j = 0; j < nprev; ++j) {
        v4f sA, sB, fac;
        squash_from(s_part + (size_t)j * SPART_ITER +
                    (size_t)bt * CHUNKS * SLICE, lane, sA, sB, fac);
        pA += fac * sA;
        pB += fac * sB;
    }

    const uint2* tb  = tile + ((size_t)bt * ADIM + a0 + r0) * 128;
    const float* lgr = logits + (size_t)(a0 + r0) * BDIM;

    v4f acc0 = (v4f){0.f, 0.f, 0.f, 0.f};
    v4f acc1 = (v4f){0.f, 0.f, 0.f, 0.f};

    // group g covers rows 3g..3g+2; per row two uint2 loads (lane, 64+lane)
    uint2 fA[6], fB[6];
#pragma unroll
    for (int u = 0; u < 6; ++u)
        fA[u] = tb[(u >> 1) * 128 + (u & 1) * 64 + lane];

#pragma unroll
    for (int g = 0; g < 6; ++g) {
        uint2* cur = (g & 1) ? fB : fA;
        uint2* nxt = (g & 1) ? fA : fB;
        if (g + 1 < 6) {
#pragma unroll
            for (int u = 0; u < 6; ++u)
                nxt[u] = tb[(3 * (g + 1) + (u >> 1)) * 128 + (u & 1) * 64 + lane];
        }
#pragma unroll
        for (int i = 0; i < 3; ++i) {
            const int rw = 3 * g + i;
            v4f va = unpack_bf16x4(cur[2 * i]);
            v4f vb = unpack_bf16x4(cur[2 * i + 1]);
            float b0 = lgr[rw * BDIM + bq];
            float b1 = lgr[rw * BDIM + 16 + bq];
            float d0 = pA.x * va.x + pA.y * va.y + pA.z * va.z + pA.w * va.w;
            float d1 = pB.x * vb.x + pB.y * vb.y + pB.z * vb.z + pB.w * vb.w;
            d0 += __shfl_xor(d0, 1, 64); d0 += __shfl_xor(d0, 2, 64);
            d1 += __shfl_xor(d1, 1, 64); d1 += __shfl_xor(d1, 2, 64);
            float e0 = __expf(b0 + d0);
            float e1 = __expf(b1 + d1);
            float uu = e0 + e1;
#pragma unroll
            for (int off = 4; off <= 32; off <<= 1)
                uu += __shfl_xor(uu, off, 64);
            float rdc = __builtin_amdgcn_rcpf(uu);
            acc0 += (e0 * rdc) * va;
            acc1 += (e1 * rdc) * vb;
        }
    }

    reduce_write(red, lane, wv, acc0, acc1,
                 s_next + ((size_t)bt * CHUNKS + chunk) * SLICE);
}

// final: reduce iter-2 chunk partials, squash, emit a_out (8192) ++ p (32768)
__global__ __launch_bounds__(512) void final_out(
    const float* __restrict__ s_part2,  // [bt][CHUNKS][SLICE]
    float* __restrict__ out)
{
    const int bt = blockIdx.x;
    const int t  = threadIdx.x;        // t = b*16 + pose
    const int pose = t & 15;

    __shared__ float sq[SLICE];
    __shared__ float ns[POSE];

    float sv = 0.f;
#pragma unroll
    for (int c = 0; c < CHUNKS; ++c)
        sv += s_part2[((size_t)bt * CHUNKS + c) * SLICE + t];

    sq[t] = sv * sv;
    __syncthreads();
    if (t < POSE) {
        float a = 0.f;
        for (int b2 = 0; b2 < BDIM; ++b2) a += sq[b2 * POSE + t];
        ns[t] = a;
    }
    __syncthreads();
    float n = ns[pose];
    float pv = sqrtf(n + EPSQ) / (1.f + n) * sv;

    out[8192 + (size_t)bt * SLICE + t] = pv;
    sq[t] = pv * pv;
    __syncthreads();
    // a_out[bt][b2][p2] = sqrt(sum_p1 p[b2][p1*4+p2]^2)
    if (t < 128) {
        const int b2 = t >> 2, p2 = t & 3;
        float a = 0.f;
#pragma unroll
        for (int p1 = 0; p1 < 4; ++p1) a += sq[b2 * POSE + p1 * 4 + p2];
        out[(size_t)bt * 128 + t] = sqrtf(a);
    }
}

extern "C" void kernel_launch(void* const* d_in, const int* in_sizes, int n_in,
                              void* d_out, int out_size, void* d_ws, size_t ws_size,
                              hipStream_t stream) {
    const float* v      = (const float*)d_in[1];   // (64,1152,32,4,4,1)
    const float* logits = (const float*)d_in[2];   // (1,1152,32,1,1,1)
    float* out = (float*)d_out;

    // ws: bf16 tile (75.5 MB) ++ s_part[3][BATCH][CHUNKS][SLICE] (6 MB).
    // All regions written before read -> no memset needed.
    uint2* tile   = (uint2*)d_ws;
    float* s_part = (float*)((char*)d_ws + (size_t)BATCH * ADIM * 128 * sizeof(uint2));

    route0_compress<<<dim3(BATCH * CHUNKS), dim3(256), 0, stream>>>(
        v, logits, tile, s_part + 0 * SPART_ITER);
    iter_tile<<<dim3(BATCH * CHUNKS), dim3(256), 0, stream>>>(
        tile, logits, s_part, s_part + 1 * SPART_ITER, 1);
    iter_tile<<<dim3(BATCH * CHUNKS), dim3(256), 0, stream>>>(
        tile, logits, s_part, s_part + 2 * SPART_ITER, 2);
    final_out<<<dim3(BATCH), dim3(512), 0, stream>>>(
        s_part + 2 * SPART_ITER, out);
}